// Round 7
// baseline (241.221 us; speedup 1.0000x reference)
//
#include <hip/hip_runtime.h>
#include <math.h>

// x fp32 [B=8, C=64, S=32*128*128=524288]
// norm over C, avg+max over S, relu, sigmoid(out^2) -> [B,C]
typedef float f32x4 __attribute__((ext_vector_type(4)));

#define NC     64
#define NS     524288
#define NB     8
#define NW     16              // waves per block (1024 threads)
#define GP     1024            // positions per group (= block threads)
#define GROUPS 2               // groups per block
#define BPB    256             // blocks per batch = NS/(GROUPS*GP)

// Round-6 structure + WAVE-PHASE ROTATION: wave w traverses the group's
// 1024 positions rotated by 64*w (256B), so the 16 waves' concurrent
// 2MB-strided channel streams sit at 16 distinct granule phases instead of
// all at phase 0 (the 2MB power-of-2 stride makes all 64 channel streams
// granule-phase-aliased; rotation is the only decorrelation the
// same-position norm coupling permits). LDS indexing absorbs the
// permutation; position-set per group is unchanged.
__global__ __launch_bounds__(1024)
void ca_partial(const float* __restrict__ x, float* __restrict__ ws) {
    __shared__ float nsq_s[NW][GP];   // 64 KB
    __shared__ float rnorm_s[GP];     // 4 KB

    const int b   = blockIdx.y;
    const int blk = blockIdx.x;
    const int t   = threadIdx.x;
    const int w   = t >> 6;     // wave id 0..15
    const int k   = t & 63;     // lane

    float run_sum[4], run_max[4];
    #pragma unroll
    for (int i = 0; i < 4; ++i) { run_sum[i] = 0.0f; run_max[i] = -INFINITY; }

    // rotated position indices for this lane (multiples of 4; mod keeps
    // float4 alignment, no group-boundary straddle)
    int pos[4];
    #pragma unroll
    for (int j = 0; j < 4; ++j)
        pos[j] = (4 * k + 256 * j + 64 * w) & (GP - 1);

    // wave w's channel-0 pointer at this block's first group (no lane offset)
    const float* base = x + (size_t)b * NC * NS + (size_t)(4 * w) * NS
                          + (size_t)blk * GROUPS * GP;

    #pragma unroll
    for (int grp = 0; grp < GROUPS; ++grp) {
        const float* gbase = base + grp * GP;

        // ---- load 4 channels x 4 float4 at rotated positions (NT) ----
        f32x4 v[4][4];                 // [channel i][subchunk j], const-indexed
        #pragma unroll
        for (int i = 0; i < 4; ++i) {
            const float* ci = gbase + (size_t)i * NS;
            #pragma unroll
            for (int j = 0; j < 4; ++j)
                v[i][j] = __builtin_nontemporal_load(
                              reinterpret_cast<const f32x4*>(ci + pos[j]));
        }

        // ---- per-position nsq partial (this wave's 4 channels) ----
        #pragma unroll
        for (int j = 0; j < 4; ++j) {
            f32x4 n = v[0][j] * v[0][j];
            n += v[1][j] * v[1][j];
            n += v[2][j] * v[2][j];
            n += v[3][j] * v[3][j];
            *reinterpret_cast<f32x4*>(&nsq_s[w][pos[j]]) = n;   // permuted row fill
        }
        __syncthreads();               // B1: nsq rows complete (each row covers
                                       // all 1024 positions, order permuted)

        // ---- column reduce: thread t owns position t (one rsqrt each) ----
        float s16 = 0.0f;
        #pragma unroll
        for (int ww = 0; ww < NW; ++ww) s16 += nsq_s[ww][t];
        rnorm_s[t] = 1.0f / fmaxf(sqrtf(s16), 1e-12f);
        __syncthreads();               // B2: rnorm visible

        // ---- normalize held registers, accumulate per-channel sum/max ----
        #pragma unroll
        for (int j = 0; j < 4; ++j) {
            const f32x4 rn = *reinterpret_cast<const f32x4*>(&rnorm_s[pos[j]]);
            #pragma unroll
            for (int i = 0; i < 4; ++i) {
                const f32x4 xn = v[i][j] * rn;
                run_sum[i] += (xn.x + xn.y) + (xn.z + xn.w);
                run_max[i] = fmaxf(run_max[i],
                                   fmaxf(fmaxf(xn.x, xn.y), fmaxf(xn.z, xn.w)));
            }
        }
    }

    // ---- one-time wave butterfly reduce, lane 0 writes partials ----
    float* wp = ws + (size_t)(b * BPB + blk) * (2 * NC);
    #pragma unroll
    for (int i = 0; i < 4; ++i) {
        float s = run_sum[i];
        float m = run_max[i];
        #pragma unroll
        for (int d = 32; d > 0; d >>= 1) {
            s += __shfl_xor(s, d, 64);
            m = fmaxf(m, __shfl_xor(m, d, 64));
        }
        if (k == 0) {
            wp[4 * w + i]      = s;   // channel c = 4w+i
            wp[NC + 4 * w + i] = m;
        }
    }
}

// Reduce BPB partials per (b,c), apply relu + sigmoid(out^2).
__global__ __launch_bounds__(1024)
void ca_final(const float* __restrict__ ws, float* __restrict__ out) {
    __shared__ float fs[16][NC];
    __shared__ float fm[16][NC];

    const int b = blockIdx.x;
    const int t = threadIdx.x;
    const int c = t & 63;
    const int q = t >> 6;      // 0..15

    float s = 0.0f, m = -INFINITY;
    for (int blk = q; blk < BPB; blk += 16) {
        const float* w = ws + (size_t)(b * BPB + blk) * (2 * NC);
        s += w[c];
        m = fmaxf(m, w[NC + c]);
    }
    fs[q][c] = s;
    fm[q][c] = m;
    __syncthreads();

    if (t < NC) {
        float ts = 0.0f, tm = -INFINITY;
        #pragma unroll
        for (int q2 = 0; q2 < 16; ++q2) {
            ts += fs[q2][t];
            tm = fmaxf(tm, fm[q2][t]);
        }
        float avg = ts * (1.0f / (float)NS);
        float o   = fmaxf(avg + tm, 0.0f);
        float att = 1.0f / (1.0f + expf(-o * o));
        out[b * NC + t] = att;
    }
}

extern "C" void kernel_launch(void* const* d_in, const int* in_sizes, int n_in,
                              void* d_out, int out_size, void* d_ws, size_t ws_size,
                              hipStream_t stream) {
    const float* x = (const float*)d_in[0];
    float* ws  = (float*)d_ws;
    float* out = (float*)d_out;

    dim3 grid1(BPB, NB);
    ca_partial<<<grid1, 1024, 0, stream>>>(x, ws);
    ca_final<<<NB, 1024, 0, stream>>>(ws, out);
}

// Round 8
// 227.165 us; speedup vs baseline: 1.0619x; 1.0619x over previous
//
#include <hip/hip_runtime.h>
#include <math.h>

// x fp32 [B=8, C=64, S=32*128*128=524288]
// norm over C, avg+max over S, relu, sigmoid(out^2) -> [B,C]
// FINAL (revert to round-5 best, 226.5 us):
//  - irreducible pattern: 64 concurrent 2MB-strided read streams (norm
//    couples all channels per position); sustains ~5.1 TB/s on gfx950.
//  - x read exactly once (FETCH_SIZE minimal), 0 bank conflicts, ~1us tail.
//  - falsified levers (rounds 3-7): reg-prefetch (scratch/regalloc), 4x
//    occupancy (null), 4KB bursts + NT + 1-rsqrt/pos (null), wave-phase
//    rotation (-6%).
#define NC    64
#define NS    524288
#define NB    8
#define NW    16               // waves per block (1024 threads)
#define P     256              // positions per chunk (64 lanes x float4)
#define CHUNK 8                // chunks per block
#define BPB   256              // blocks per batch = NS/(CHUNK*P)

__global__ __launch_bounds__(1024)
void ca_partial(const float* __restrict__ x, float* __restrict__ ws) {
    __shared__ float nsq_s[2][NW][P];   // 32 KB, parity double-buffered

    const int b   = blockIdx.y;
    const int blk = blockIdx.x;
    const int t   = threadIdx.x;
    const int w   = t >> 6;     // wave id 0..15
    const int k   = t & 63;     // lane

    float run_sum[4], run_max[4];
    #pragma unroll
    for (int i = 0; i < 4; ++i) { run_sum[i] = 0.0f; run_max[i] = -INFINITY; }

    // 4 channel-stream pointers (channels 4w+i), advanced by P each chunk
    const float* p0 = x + (size_t)b * NC * NS + (size_t)(4 * w + 0) * NS
                        + (size_t)blk * CHUNK * P + 4 * k;
    const float* p1 = p0 + (size_t)NS;
    const float* p2 = p0 + (size_t)2 * NS;
    const float* p3 = p0 + (size_t)3 * NS;

    for (int ch = 0; ch < CHUNK; ++ch) {
        // ---- load 4 channels x float4 (coalesced 16B/lane) ----
        const float4 v0 = *reinterpret_cast<const float4*>(p0);
        const float4 v1 = *reinterpret_cast<const float4*>(p1);
        const float4 v2 = *reinterpret_cast<const float4*>(p2);
        const float4 v3 = *reinterpret_cast<const float4*>(p3);
        p0 += P; p1 += P; p2 += P; p3 += P;

        // ---- per-position norm^2 partial over this wave's 4 channels ----
        float nx = v0.x * v0.x, ny = v0.y * v0.y, nz = v0.z * v0.z, nw2 = v0.w * v0.w;
        nx = fmaf(v1.x, v1.x, nx); ny = fmaf(v1.y, v1.y, ny);
        nz = fmaf(v1.z, v1.z, nz); nw2 = fmaf(v1.w, v1.w, nw2);
        nx = fmaf(v2.x, v2.x, nx); ny = fmaf(v2.y, v2.y, ny);
        nz = fmaf(v2.z, v2.z, nz); nw2 = fmaf(v2.w, v2.w, nw2);
        nx = fmaf(v3.x, v3.x, nx); ny = fmaf(v3.y, v3.y, ny);
        nz = fmaf(v3.z, v3.z, nz); nw2 = fmaf(v3.w, v3.w, nw2);

        // ---- cross-wave exchange (parity buffer, one barrier per chunk) ----
        const int par = ch & 1;
        *reinterpret_cast<float4*>(&nsq_s[par][w][4 * k]) = make_float4(nx, ny, nz, nw2);
        __syncthreads();

        float tx = 0.f, ty = 0.f, tz = 0.f, tw = 0.f;
        #pragma unroll
        for (int ww = 0; ww < NW; ++ww) {
            const float4 q = *reinterpret_cast<const float4*>(&nsq_s[par][ww][4 * k]);
            tx += q.x; ty += q.y; tz += q.z; tw += q.w;
        }
        const float rx = 1.0f / fmaxf(sqrtf(tx), 1e-12f);
        const float ry = 1.0f / fmaxf(sqrtf(ty), 1e-12f);
        const float rz = 1.0f / fmaxf(sqrtf(tz), 1e-12f);
        const float rw = 1.0f / fmaxf(sqrtf(tw), 1e-12f);

        // ---- normalize held registers, accumulate per-channel sum/max ----
        run_sum[0] = fmaf(v0.x, rx, run_sum[0]); run_sum[0] = fmaf(v0.y, ry, run_sum[0]);
        run_sum[0] = fmaf(v0.z, rz, run_sum[0]); run_sum[0] = fmaf(v0.w, rw, run_sum[0]);
        run_sum[1] = fmaf(v1.x, rx, run_sum[1]); run_sum[1] = fmaf(v1.y, ry, run_sum[1]);
        run_sum[1] = fmaf(v1.z, rz, run_sum[1]); run_sum[1] = fmaf(v1.w, rw, run_sum[1]);
        run_sum[2] = fmaf(v2.x, rx, run_sum[2]); run_sum[2] = fmaf(v2.y, ry, run_sum[2]);
        run_sum[2] = fmaf(v2.z, rz, run_sum[2]); run_sum[2] = fmaf(v2.w, rw, run_sum[2]);
        run_sum[3] = fmaf(v3.x, rx, run_sum[3]); run_sum[3] = fmaf(v3.y, ry, run_sum[3]);
        run_sum[3] = fmaf(v3.w, rw, run_sum[3]); run_sum[3] = fmaf(v3.z, rz, run_sum[3]);

        run_max[0] = fmaxf(run_max[0], fmaxf(fmaxf(v0.x * rx, v0.y * ry),
                                             fmaxf(v0.z * rz, v0.w * rw)));
        run_max[1] = fmaxf(run_max[1], fmaxf(fmaxf(v1.x * rx, v1.y * ry),
                                             fmaxf(v1.z * rz, v1.w * rw)));
        run_max[2] = fmaxf(run_max[2], fmaxf(fmaxf(v2.x * rx, v2.y * ry),
                                             fmaxf(v2.z * rz, v2.w * rw)));
        run_max[3] = fmaxf(run_max[3], fmaxf(fmaxf(v3.x * rx, v3.y * ry),
                                             fmaxf(v3.z * rz, v3.w * rw)));
    }

    // ---- one-time wave butterfly reduce, lane 0 writes partials ----
    float* wp = ws + (size_t)(b * BPB + blk) * (2 * NC);
    #pragma unroll
    for (int i = 0; i < 4; ++i) {
        float s = run_sum[i];
        float m = run_max[i];
        #pragma unroll
        for (int d = 32; d > 0; d >>= 1) {
            s += __shfl_xor(s, d, 64);
            m = fmaxf(m, __shfl_xor(m, d, 64));
        }
        if (k == 0) {
            wp[4 * w + i]      = s;   // channel c = 4w+i
            wp[NC + 4 * w + i] = m;
        }
    }
}

// Reduce BPB partials per (b,c), apply relu + sigmoid(out^2).
__global__ __launch_bounds__(1024)
void ca_final(const float* __restrict__ ws, float* __restrict__ out) {
    __shared__ float fs[16][NC];
    __shared__ float fm[16][NC];

    const int b = blockIdx.x;
    const int t = threadIdx.x;
    const int c = t & 63;
    const int q = t >> 6;      // 0..15

    float s = 0.0f, m = -INFINITY;
    for (int blk = q; blk < BPB; blk += 16) {
        const float* w = ws + (size_t)(b * BPB + blk) * (2 * NC);
        s += w[c];
        m = fmaxf(m, w[NC + c]);
    }
    fs[q][c] = s;
    fm[q][c] = m;
    __syncthreads();

    if (t < NC) {
        float ts = 0.0f, tm = -INFINITY;
        #pragma unroll
        for (int q2 = 0; q2 < 16; ++q2) {
            ts += fs[q2][t];
            tm = fmaxf(tm, fm[q2][t]);
        }
        float avg = ts * (1.0f / (float)NS);
        float o   = fmaxf(avg + tm, 0.0f);
        float att = 1.0f / (1.0f + expf(-o * o));
        out[b * NC + t] = att;
    }
}

extern "C" void kernel_launch(void* const* d_in, const int* in_sizes, int n_in,
                              void* d_out, int out_size, void* d_ws, size_t ws_size,
                              hipStream_t stream) {
    const float* x = (const float*)d_in[0];
    float* ws  = (float*)d_ws;
    float* out = (float*)d_out;

    dim3 grid1(BPB, NB);
    ca_partial<<<grid1, 1024, 0, stream>>>(x, ws);
    ca_final<<<NB, 1024, 0, stream>>>(ws, out);
}